// Round 8
// baseline (633.334 us; speedup 1.0000x reference)
//
#include <hip/hip_runtime.h>

#define T_TOKENS 32768
#define DIM 512
#define FDIM 2048
#define NEXP 8

typedef __attribute__((ext_vector_type(4))) float f32x4;
typedef __attribute__((ext_vector_type(8))) short bf16x8;

__device__ __forceinline__ unsigned short f2bf(float f) {
  unsigned int u = __float_as_uint(f);
  u += 0x7FFFu + ((u >> 16) & 1u);   // round-to-nearest-even
  return (unsigned short)(u >> 16);
}

// Barrier that does NOT drain vmcnt (R6, kept: -15%). hipcc's __syncthreads
// emits "s_waitcnt vmcnt(0) lgkmcnt(0); s_barrier" which kills in-flight
// register prefetches. Only LDS writes (lgkmcnt) need cross-wave visibility.
#define LGKM_BARRIER()                                        \
  do {                                                        \
    asm volatile("s_waitcnt lgkmcnt(0)" ::: "memory");        \
    __builtin_amdgcn_s_barrier();                             \
  } while (0)

// Pack W1 [E][D][F] fp32 -> fragment-linear bf16, line-coalesced reads via LDS.
// W1p[((e*128+ft)*16+kci)*512 + l*8 + j] = bf16(W1[e][kci*32+(l>>4)*8+j][ft*16+(l&15)])
__global__ void pack_w1_kernel(const float* __restrict__ W1, unsigned short* __restrict__ W1p) {
  __shared__ float L[512][17];
  const int b = blockIdx.x;          // e*128 + ft
  const int e = b >> 7, ft = b & 127;
  const int t = threadIdx.x;         // 256
  const int c = t & 15, r0 = t >> 4;
  const float* src = W1 + (long)e * 512 * 2048 + ft * 16 + c;
  #pragma unroll
  for (int ch = 0; ch < 32; ch++) {
    int r = ch * 16 + r0;
    L[r][c] = src[(long)r * 2048];
  }
  __syncthreads();
  #pragma unroll
  for (int s = 0; s < 4; s++) {
    int slot = s * 256 + t;
    int kci = slot >> 6, l = slot & 63;
    unsigned short tmp[8];
    #pragma unroll
    for (int j = 0; j < 8; j++)
      tmp[j] = f2bf(L[kci * 32 + (l >> 4) * 8 + j][l & 15]);
    *(ushort4*)(W1p + ((long)b * 16 + kci) * 512 + l * 8)     = *(ushort4*)&tmp[0];
    *(ushort4*)(W1p + ((long)b * 16 + kci) * 512 + l * 8 + 4) = *(ushort4*)&tmp[4];
  }
}

// Pack W2 [E][F][D] fp32 -> fragment-linear bf16, line-coalesced reads via LDS.
// W2p[((e*64+kc2i)*32+dt)*512 + l*8 + j] = bf16(W2[e][kc2i*32+(l>>4)*8+j][dt*16+(l&15)])
__global__ void pack_w2_kernel(const float* __restrict__ W2, unsigned short* __restrict__ W2p) {
  __shared__ float L[512][17];
  const int b = blockIdx.x;          // e*32 + dt
  const int e = b >> 5, dt = b & 31;
  const int t = threadIdx.x;
  const int c = t & 15, r0 = t >> 4;
  for (int ch = 0; ch < 4; ch++) {   // f in chunks of 512
    if (ch) __syncthreads();
    const float* src = W2 + ((long)e * 2048 + ch * 512) * 512 + dt * 16 + c;
    #pragma unroll
    for (int cc = 0; cc < 32; cc++) {
      int r = cc * 16 + r0;
      L[r][c] = src[(long)r * 512];
    }
    __syncthreads();
    #pragma unroll
    for (int s = 0; s < 4; s++) {
      int slot = s * 256 + t;
      int kciL = slot >> 6, l = slot & 63;
      unsigned short tmp[8];
      #pragma unroll
      for (int j = 0; j < 8; j++)
        tmp[j] = f2bf(L[kciL * 32 + (l >> 4) * 8 + j][l & 15]);
      long tt = (long)(e * 64 + ch * 16 + kciL) * 32 + dt;
      *(ushort4*)(W2p + tt * 512 + l * 8)     = *(ushort4*)&tmp[0];
      *(ushort4*)(W2p + tt * 512 + l * 8 + 4) = *(ushort4*)&tmp[4];
    }
  }
}

// one thread per token; per-block LDS histogram -> 8 global atomics per block.
__global__ void router_kernel(const float* __restrict__ x, const float* __restrict__ Wr,
                              const float* __restrict__ br, int* __restrict__ counts,
                              int* __restrict__ tok_list, float* __restrict__ wt_list,
                              int* __restrict__ slots) {
  __shared__ float WrS[NEXP][DIM];
  __shared__ int lcnt[NEXP];
  __shared__ int lbase[NEXP];
  const int tid = threadIdx.x;   // 256
  for (int i = tid; i < NEXP * DIM; i += 256) {
    int e = i >> 9, d = i & (DIM - 1);
    WrS[e][d] = Wr[d * NEXP + e];
  }
  if (tid < NEXP) lcnt[tid] = 0;
  __syncthreads();

  const int t = blockIdx.x * 256 + tid;
  const float* xr = x + (long)t * DIM;
  float acc[NEXP];
  #pragma unroll
  for (int e = 0; e < NEXP; e++) acc[e] = br[e];
  for (int d = 0; d < DIM; d += 4) {
    const float4 xv = *(const float4*)(xr + d);
    #pragma unroll
    for (int e = 0; e < NEXP; e++)
      acc[e] += xv.x * WrS[e][d] + xv.y * WrS[e][d + 1] +
                xv.z * WrS[e][d + 2] + xv.w * WrS[e][d + 3];
  }
  int e0 = 0; float v0 = acc[0];
  #pragma unroll
  for (int e = 1; e < NEXP; e++) if (acc[e] > v0) { v0 = acc[e]; e0 = e; }
  int e1 = -1; float v1 = -3.4e38f;
  #pragma unroll
  for (int e = 0; e < NEXP; e++) if (e != e0 && acc[e] > v1) { v1 = acc[e]; e1 = e; }
  float w0 = 1.f / (1.f + __expf(v1 - v0));
  float w1 = 1.f - w0;

  int l0 = atomicAdd(&lcnt[e0], 1);
  int l1 = atomicAdd(&lcnt[e1], 1);
  __syncthreads();
  if (tid < NEXP) lbase[tid] = atomicAdd(&counts[tid], lcnt[tid]);
  __syncthreads();
  int s0 = lbase[e0] + l0;
  tok_list[e0 * T_TOKENS + s0] = t; wt_list[e0 * T_TOKENS + s0] = w0;
  int s1 = lbase[e1] + l1;
  tok_list[e1 * T_TOKENS + s1] = t; wt_list[e1 * T_TOKENS + s1] = w1;
  if (slots) {
    slots[2 * t]     = e0 * T_TOKENS + s0;
    slots[2 * t + 1] = e1 * T_TOKENS + s1;
  }
}

// load 8 consecutive kci fragment-lines of this wave's ft column block
#define LD8(dst, ptr, kbase)                                    \
  _Pragma("unroll")                                             \
  for (int i = 0; i < 8; i++)                                   \
    dst[i] = *(const bf16x8*)((ptr) + (kbase + i) * 512);

// 8 kci x 4 m-tiles of MFMA; af re-read from Xs per (kci, mt)
#define MF8(src, kbase)                                                            \
  _Pragma("unroll")                                                                \
  for (int i = 0; i < 8; i++) {                                                    \
    int kci = (kbase) + i;                                                         \
    int xo = ((kci * 4 + g) ^ xsw) << 3;                                           \
    _Pragma("unroll")                                                              \
    for (int mt = 0; mt < 4; mt++) {                                               \
      bf16x8 af = *(const bf16x8*)&Xs[(mt * 16 + ln) * 512 + xo];                  \
      H[mt] = __builtin_amdgcn_mfma_f32_16x16x32_bf16(af, src[i], H[mt], 0, 0, 0); \
    }                                                                              \
  }

#define LD_W2(klbase)                                                             \
  _Pragma("unroll")                                                               \
  for (int kl = klbase; kl < klbase + 2; kl++) {                                  \
    const unsigned short* w2b =                                                   \
        W2p + ((long)((e * 64 + (fc >> 5) + kl) * 32 + wave * 4) * 64 + lane) * 8;\
    _Pragma("unroll")                                                             \
    for (int nt = 0; nt < 4; nt++)                                                \
      w2r[kl][nt] = *(const bf16x8*)(w2b + nt * 512);                             \
  }

// R8: 2 blocks/CU, this time properly controlled. Evidence: R7 sits at
// 4000 cyc/SIMD/iter with MFMA 1280 (32%), LDS ~40%, VMEM ~25% -- no pipe
// saturated; both resident waves stall together on dependency waits. R3's
// occupancy test was invalidated by its VGPR 112->64 squeeze (Yacc spills
// = the +70MB WRITE / +400MB FETCH scratch traffic), not by occupancy.
// Change: single-buffer Hs -> LDS 80KB (2x80 = 160 exactly); keep
// launch_bounds(512,2) whose empirical VGPR cap is 128 = 4 waves/SIMD per
// m69. Cost: 2nd LGKM barrier per fc-iter (protect single-buffered Hs);
// covered by the sibling block's waves. Co-resident blocks share the same
// expert (blockIdx differ by 256 -> same e) so L2 weight residency holds.
template <bool USE_PARTIAL>
__global__ __launch_bounds__(512, 2) void ffn_kernel(
    const float* __restrict__ x,
    const unsigned short* __restrict__ W1p,
    const unsigned short* __restrict__ W2p,
    const float* __restrict__ b1, const float* __restrict__ b2,
    const int* __restrict__ counts,
    const int* __restrict__ tok_list, const float* __restrict__ wt_list,
    float* __restrict__ partial,
    float* __restrict__ out) {
  __shared__ unsigned short Xs[64 * 512];   // 64 KB
  __shared__ unsigned short Hs[64 * 128];   // 16 KB single-buffered -> 80 KB total

  const int e = blockIdx.x & 7;        // expert -> XCD pinning
  const int tile = blockIdx.x >> 3;
  const int cnt = counts[e];
  const int m0 = tile * 64;
  if (m0 >= cnt) return;
  const int rows = min(64, cnt - m0);

  // compact base row for this expert in the partial buffer
  int pbase = 0;
  if (USE_PARTIAL) {
    #pragma unroll
    for (int i = 0; i < NEXP; i++) pbase += (i < e) ? counts[i] : 0;
  }

  const int tid = threadIdx.x;
  const int wave = tid >> 6, lane = tid & 63;
  const int g = lane >> 4, ln = lane & 15;

  // stage gathered X tile (fp32 -> bf16), XOR-swizzled; nontemporal reads
  #pragma unroll 4
  for (int c = tid; c < 64 * 128; c += 512) {
    int r = c >> 7, q = c & 127;
    ushort4 bv = {0, 0, 0, 0};
    if (r < rows) {
      int tk = tok_list[e * T_TOKENS + m0 + r];
      const f32x4 v = __builtin_nontemporal_load((const f32x4*)(x + (long)tk * DIM + q * 4));
      bv.x = f2bf(v[0]); bv.y = f2bf(v[1]); bv.z = f2bf(v[2]); bv.w = f2bf(v[3]);
    }
    int addr = r * 512 + ((((q >> 1) ^ (r & 7)) << 3) | ((q & 1) << 2));
    *(ushort4*)&Xs[addr] = bv;
  }
  LGKM_BARRIER();

  const f32x4 zero4 = {0.f, 0.f, 0.f, 0.f};
  f32x4 Yacc[4][4];
  #pragma unroll
  for (int a = 0; a < 4; a++)
    #pragma unroll
    for (int b = 0; b < 4; b++) Yacc[a][b] = zero4;

  const int xsw = ln & 7;

  // this wave's W1 column block: ft = fc/16 + wave (8 waves cover 8 ft/iter)
  const unsigned short* const w1b_first =
      W1p + ((long)(e * 128 + wave) * 16) * 512 + lane * 8;
  const unsigned short* w1b = w1b_first;

  bf16x8 wA[8], wB[8], w2r[4][4];
  // prologue: prefetch iter-0 kci 0..7 (one exposed wait per block)
  LD8(wA, w1b, 0);

  for (int fc = 0; fc < FDIM; fc += 128) {
    unsigned short* Hp = &Hs[0];
    f32x4 H[4];
    #pragma unroll
    for (int mt = 0; mt < 4; mt++) H[mt] = zero4;

    LD8(wB, w1b, 8);     // this iter kci 8..15, covered by MF8(wA)
    __builtin_amdgcn_s_setprio(1);
    MF8(wA, 0);          // prefetched last iter -> wait covered
    __builtin_amdgcn_s_setprio(0);
    LD_W2(0);            // GEMM2 kl 0,1 prefetch (survives barriers)
    __builtin_amdgcn_s_setprio(1);
    MF8(wB, 8);          // covered by MF8(wA) ~620 issued cycles
    __builtin_amdgcn_s_setprio(0);
    // next-iter W1 base (last iter: re-point at iter-0 lines; the prefetch
    // reads are valid but their values are never consumed)
    w1b = (fc + 128 < FDIM) ? (w1b + 8 * 16 * 512) : w1b_first;
    LD8(wA, w1b, 0);     // next-iter kci 0..7; waited next iter after
                         // Hs-write + barrier + GEMM2 (>=1500 cycles cover)

    // barrier A: previous iter's GEMM2 must finish reading Hs before rewrite.
    // GEMM2(i-1) and GEMM1(i) both run between barrier B(i-1) and here.
    LGKM_BARRIER();

    // bias + relu -> Hs (C-layout: col fl = wave*16+ln, row mt*16+g*4+i)
    {
      float b1v = b1[e * FDIM + fc + wave * 16 + ln];
      int fl = wave * 16 + ln;
      #pragma unroll
      for (int mt = 0; mt < 4; mt++) {
        #pragma unroll
        for (int i = 0; i < 4; i++) {
          int m = mt * 16 + g * 4 + i;
          int addr = m * 128 + ((((fl >> 3) ^ (m & 7)) << 3) | (fl & 7));
          Hp[addr] = f2bf(fmaxf(H[mt][i] + b1v, 0.f));
        }
      }
    }
    // barrier B: Hs writes visible before GEMM2 reads; weight prefetches
    // stay in flight (lgkmcnt-only drain).
    LGKM_BARRIER();

    LD_W2(2);          // prefetch kl 2,3 under kl 0,1 MFMAs

    __builtin_amdgcn_s_setprio(1);
    #pragma unroll
    for (int kl = 0; kl < 4; kl++) {
      bf16x8 ha[4];
      #pragma unroll
      for (int mt = 0; mt < 4; mt++) {
        int m = mt * 16 + ln;
        ha[mt] = *(const bf16x8*)&Hp[m * 128 + ((((kl * 4 + g) ^ (m & 7)) << 3))];
      }
      #pragma unroll
      for (int nt = 0; nt < 4; nt++)
        #pragma unroll
        for (int mt = 0; mt < 4; mt++)
          Yacc[mt][nt] = __builtin_amdgcn_mfma_f32_16x16x32_bf16(ha[mt], w2r[kl][nt], Yacc[mt][nt], 0, 0, 0);
    }
    __builtin_amdgcn_s_setprio(0);
  }

  // epilogue: (Y + b2) * token_weight
  #pragma unroll
  for (int mt = 0; mt < 4; mt++) {
    #pragma unroll
    for (int i = 0; i < 4; i++) {
      int m = mt * 16 + g * 4 + i;
      if (m < rows) {
        float w = wt_list[e * T_TOKENS + m0 + m];
        if (USE_PARTIAL) {
          // coalesced non-atomic store of this assignment's weighted row slice
          float* dst = partial + ((long)(pbase + m0 + m)) * DIM;
          #pragma unroll
          for (int nt = 0; nt < 4; nt++) {
            int d = (wave * 4 + nt) * 16 + ln;
            __builtin_nontemporal_store((Yacc[mt][nt][i] + b2[e * DIM + d]) * w, dst + d);
          }
        } else {
          int tk = tok_list[e * T_TOKENS + m0 + m];
          #pragma unroll
          for (int nt = 0; nt < 4; nt++) {
            int d = (wave * 4 + nt) * 16 + ln;
            float v = (Yacc[mt][nt][i] + b2[e * DIM + d]) * w;
            atomicAdd(out + (long)tk * DIM + d, v);
          }
        }
      }
    }
  }
}

// out[t] = partial[row(slots[2t])] + partial[row(slots[2t+1])] ; pure
// streaming, no RMW. row(slot) = prefix[e] + s with slot = e*T_TOKENS + s.
__global__ __launch_bounds__(256) void combine_kernel(
    const float* __restrict__ partial, const int* __restrict__ slots,
    const int* __restrict__ counts, float* __restrict__ out) {
  __shared__ int pre[NEXP];
  if (threadIdx.x == 0) {
    int a = 0;
    #pragma unroll
    for (int i = 0; i < NEXP; i++) { pre[i] = a; a += counts[i]; }
  }
  __syncthreads();
  const int tid = threadIdx.x;
  const int tk = blockIdx.x * 2 + (tid >> 7);
  const int q = (tid & 127) << 2;
  const int2 sp = *(const int2*)(slots + 2 * tk);
  const long r0 = pre[sp.x >> 15] + (sp.x & (T_TOKENS - 1));
  const long r1 = pre[sp.y >> 15] + (sp.y & (T_TOKENS - 1));
  const f32x4 a = __builtin_nontemporal_load((const f32x4*)(partial + r0 * DIM + q));
  const f32x4 b = __builtin_nontemporal_load((const f32x4*)(partial + r1 * DIM + q));
  f32x4 r = a + b;
  __builtin_nontemporal_store(r, (f32x4*)(out + (long)tk * DIM + q));
}

extern "C" void kernel_launch(void* const* d_in, const int* in_sizes, int n_in,
                              void* d_out, int out_size, void* d_ws, size_t ws_size,
                              hipStream_t stream) {
  (void)in_sizes; (void)n_in; (void)out_size;
  const float* x  = (const float*)d_in[0];
  const float* Wr = (const float*)d_in[1];
  const float* br = (const float*)d_in[2];
  const float* W1 = (const float*)d_in[3];
  const float* b1 = (const float*)d_in[4];
  const float* W2 = (const float*)d_in[5];
  const float* b2 = (const float*)d_in[6];
  float* out = (float*)d_out;

  char* ws = (char*)d_ws;
  // layout (bytes):
  //   counts   @ 0          (1,024)
  //   tok_list @ 1,024      (1,048,576)
  //   wt_list  @ 1,049,600  (1,048,576)
  //   slots    @ 2,098,176  (262,144)
  //   W1p      @ 2,360,320  (16,777,216)
  //   W2p      @ 19,137,536 (16,777,216)
  //   partial  @ 35,914,752 (134,217,728 = 2*T rows x 512 f32) -> end 170,132,480
  int*            counts   = (int*)(ws);
  int*            tok_list = (int*)(ws + 1024);
  float*          wt_list  = (float*)(ws + 1049600);
  int*            slots    = (int*)(ws + 2098176);
  unsigned short* W1p      = (unsigned short*)(ws + 2360320);
  unsigned short* W2p      = (unsigned short*)(ws + 19137536);
  float*          partial  = (float*)(ws + 35914752);
  const size_t need_partial = 35914752ull + (size_t)T_TOKENS * 2 * DIM * sizeof(float);
  const bool use_partial = ws_size >= need_partial;

  hipMemsetAsync(counts, 0, 1024, stream);
  pack_w1_kernel<<<NEXP * 128, 256, 0, stream>>>(W1, W1p);
  pack_w2_kernel<<<NEXP * 32, 256, 0, stream>>>(W2, W2p);

  if (use_partial) {
    router_kernel<<<T_TOKENS / 256, 256, 0, stream>>>(x, Wr, br, counts, tok_list, wt_list, slots);
    ffn_kernel<true><<<T_TOKENS / 64 * NEXP, 512, 0, stream>>>(
        x, W1p, W2p, b1, b2, counts, tok_list, wt_list, partial, out);
    combine_kernel<<<T_TOKENS / 2, 256, 0, stream>>>(partial, slots, counts, out);
  } else {
    // fallback: original atomic-accumulate path
    hipMemsetAsync(out, 0, (size_t)T_TOKENS * DIM * sizeof(float), stream);
    router_kernel<<<T_TOKENS / 256, 256, 0, stream>>>(x, Wr, br, counts, tok_list, wt_list, nullptr);
    ffn_kernel<false><<<T_TOKENS / 64 * NEXP, 512, 0, stream>>>(
        x, W1p, W2p, b1, b2, counts, tok_list, wt_list, nullptr, out);
  }
}

// Round 9
// 609.783 us; speedup vs baseline: 1.0386x; 1.0386x over previous
//
#include <hip/hip_runtime.h>

#define T_TOKENS 32768
#define DIM 512
#define FDIM 2048
#define NEXP 8

typedef __attribute__((ext_vector_type(4))) float f32x4;
typedef __attribute__((ext_vector_type(8))) short bf16x8;

__device__ __forceinline__ unsigned short f2bf(float f) {
  unsigned int u = __float_as_uint(f);
  u += 0x7FFFu + ((u >> 16) & 1u);   // round-to-nearest-even
  return (unsigned short)(u >> 16);
}

// Barrier that does NOT drain vmcnt (R6, kept: -15%). hipcc's __syncthreads
// emits "s_waitcnt vmcnt(0) lgkmcnt(0); s_barrier" which kills in-flight
// register prefetches. Only LDS writes (lgkmcnt) need cross-wave visibility.
#define LGKM_BARRIER()                                        \
  do {                                                        \
    asm volatile("s_waitcnt lgkmcnt(0)" ::: "memory");        \
    __builtin_amdgcn_s_barrier();                             \
  } while (0)

// Pack W1 [E][D][F] fp32 -> fragment-linear bf16, line-coalesced reads via LDS.
// W1p[((e*128+ft)*16+kci)*512 + l*8 + j] = bf16(W1[e][kci*32+(l>>4)*8+j][ft*16+(l&15)])
__global__ void pack_w1_kernel(const float* __restrict__ W1, unsigned short* __restrict__ W1p) {
  __shared__ float L[512][17];
  const int b = blockIdx.x;          // e*128 + ft
  const int e = b >> 7, ft = b & 127;
  const int t = threadIdx.x;         // 256
  const int c = t & 15, r0 = t >> 4;
  const float* src = W1 + (long)e * 512 * 2048 + ft * 16 + c;
  #pragma unroll
  for (int ch = 0; ch < 32; ch++) {
    int r = ch * 16 + r0;
    L[r][c] = src[(long)r * 2048];
  }
  __syncthreads();
  #pragma unroll
  for (int s = 0; s < 4; s++) {
    int slot = s * 256 + t;
    int kci = slot >> 6, l = slot & 63;
    unsigned short tmp[8];
    #pragma unroll
    for (int j = 0; j < 8; j++)
      tmp[j] = f2bf(L[kci * 32 + (l >> 4) * 8 + j][l & 15]);
    *(ushort4*)(W1p + ((long)b * 16 + kci) * 512 + l * 8)     = *(ushort4*)&tmp[0];
    *(ushort4*)(W1p + ((long)b * 16 + kci) * 512 + l * 8 + 4) = *(ushort4*)&tmp[4];
  }
}

// Pack W2 [E][F][D] fp32 -> fragment-linear bf16, line-coalesced reads via LDS.
// W2p[((e*64+kc2i)*32+dt)*512 + l*8 + j] = bf16(W2[e][kc2i*32+(l>>4)*8+j][dt*16+(l&15)])
__global__ void pack_w2_kernel(const float* __restrict__ W2, unsigned short* __restrict__ W2p) {
  __shared__ float L[512][17];
  const int b = blockIdx.x;          // e*32 + dt
  const int e = b >> 5, dt = b & 31;
  const int t = threadIdx.x;
  const int c = t & 15, r0 = t >> 4;
  for (int ch = 0; ch < 4; ch++) {   // f in chunks of 512
    if (ch) __syncthreads();
    const float* src = W2 + ((long)e * 2048 + ch * 512) * 512 + dt * 16 + c;
    #pragma unroll
    for (int cc = 0; cc < 32; cc++) {
      int r = cc * 16 + r0;
      L[r][c] = src[(long)r * 512];
    }
    __syncthreads();
    #pragma unroll
    for (int s = 0; s < 4; s++) {
      int slot = s * 256 + t;
      int kciL = slot >> 6, l = slot & 63;
      unsigned short tmp[8];
      #pragma unroll
      for (int j = 0; j < 8; j++)
        tmp[j] = f2bf(L[kciL * 32 + (l >> 4) * 8 + j][l & 15]);
      long tt = (long)(e * 64 + ch * 16 + kciL) * 32 + dt;
      *(ushort4*)(W2p + tt * 512 + l * 8)     = *(ushort4*)&tmp[0];
      *(ushort4*)(W2p + tt * 512 + l * 8 + 4) = *(ushort4*)&tmp[4];
    }
  }
}

// one thread per token; per-block LDS histogram -> 8 global atomics per block.
__global__ void router_kernel(const float* __restrict__ x, const float* __restrict__ Wr,
                              const float* __restrict__ br, int* __restrict__ counts,
                              int* __restrict__ tok_list, float* __restrict__ wt_list,
                              int* __restrict__ slots) {
  __shared__ float WrS[NEXP][DIM];
  __shared__ int lcnt[NEXP];
  __shared__ int lbase[NEXP];
  const int tid = threadIdx.x;   // 256
  for (int i = tid; i < NEXP * DIM; i += 256) {
    int e = i >> 9, d = i & (DIM - 1);
    WrS[e][d] = Wr[d * NEXP + e];
  }
  if (tid < NEXP) lcnt[tid] = 0;
  __syncthreads();

  const int t = blockIdx.x * 256 + tid;
  const float* xr = x + (long)t * DIM;
  float acc[NEXP];
  #pragma unroll
  for (int e = 0; e < NEXP; e++) acc[e] = br[e];
  for (int d = 0; d < DIM; d += 4) {
    const float4 xv = *(const float4*)(xr + d);
    #pragma unroll
    for (int e = 0; e < NEXP; e++)
      acc[e] += xv.x * WrS[e][d] + xv.y * WrS[e][d + 1] +
                xv.z * WrS[e][d + 2] + xv.w * WrS[e][d + 3];
  }
  int e0 = 0; float v0 = acc[0];
  #pragma unroll
  for (int e = 1; e < NEXP; e++) if (acc[e] > v0) { v0 = acc[e]; e0 = e; }
  int e1 = -1; float v1 = -3.4e38f;
  #pragma unroll
  for (int e = 0; e < NEXP; e++) if (e != e0 && acc[e] > v1) { v1 = acc[e]; e1 = e; }
  float w0 = 1.f / (1.f + __expf(v1 - v0));
  float w1 = 1.f - w0;

  int l0 = atomicAdd(&lcnt[e0], 1);
  int l1 = atomicAdd(&lcnt[e1], 1);
  __syncthreads();
  if (tid < NEXP) lbase[tid] = atomicAdd(&counts[tid], lcnt[tid]);
  __syncthreads();
  int s0 = lbase[e0] + l0;
  tok_list[e0 * T_TOKENS + s0] = t; wt_list[e0 * T_TOKENS + s0] = w0;
  int s1 = lbase[e1] + l1;
  tok_list[e1 * T_TOKENS + s1] = t; wt_list[e1 * T_TOKENS + s1] = w1;
  if (slots) {
    slots[2 * t]     = e0 * T_TOKENS + s0;
    slots[2 * t + 1] = e1 * T_TOKENS + s1;
  }
}

// Load 4 kci lines for BOTH of this wave's ft tiles (ftA at w1b, ftB at +16 lines)
#define LD4x2(dst, kbase)                                         \
  _Pragma("unroll")                                               \
  for (int i = 0; i < 4; i++) {                                   \
    dst[i]     = *(const bf16x8*)(w1b + (kbase + i) * 512);       \
    dst[4 + i] = *(const bf16x8*)(w1b + (16 + kbase + i) * 512);  \
  }

// 4 kci x 4 mt; each af read from Xs feeds TWO MFMAs (ftA -> HA, ftB -> HB):
// halves GEMM1 LDS reads vs R7 (the dominant pipe, ~66% busy).
#define MF4x2(src, kbase)                                                            \
  _Pragma("unroll")                                                                  \
  for (int i = 0; i < 4; i++) {                                                      \
    int kci = (kbase) + i;                                                           \
    int xo = ((kci * 4 + g) ^ xsw) << 3;                                             \
    _Pragma("unroll")                                                                \
    for (int mt = 0; mt < 4; mt++) {                                                 \
      bf16x8 af = *(const bf16x8*)&Xs[(mt * 16 + ln) * 512 + xo];                    \
      HA[mt] = __builtin_amdgcn_mfma_f32_16x16x32_bf16(af, src[i],     HA[mt], 0, 0, 0); \
      HB[mt] = __builtin_amdgcn_mfma_f32_16x16x32_bf16(af, src[4 + i], HB[mt], 0, 0, 0); \
    }                                                                                \
  }

#define LD_W2B(buf, kl)                                                           \
  do {                                                                            \
    const unsigned short* w2b =                                                   \
        W2p + ((long)((e * 64 + (fc >> 5) + (kl)) * 32 + wave * 4) * 64 + lane) * 8;\
    _Pragma("unroll")                                                             \
    for (int nt = 0; nt < 4; nt++)                                                \
      buf[nt] = *(const bf16x8*)(w2b + nt * 512);                                 \
  } while (0)

// R9: attack the LDS pipe (measured dominant: GEMM1 A-reads 6.1K + ha 1.5K +
// writes/conflicts 2.5K ~ 10.7K of 16.3K cyc/CU-iter; MFMA only 4.1K).
// (1) fc-iter spans 256 F; each wave owns TWO adjacent ft tiles -> each Xs
//     A-fragment read feeds 2 MFMAs (A-reads halve); W1 stays dup-free.
// (2) Hs = single 64x256 buffer (32KB; total LDS 96KB) -> barriers per 128F
//     halve vs R8.
// (3) Hs swizzle key m&7 -> m&15: write instrs now span 8 slots x 4 banks =
//     all 32 banks (2-way, free) vs 16 banks (4-way). Reads stay 2-way.
// Occupancy note (R3/R8 lesson): unified VGPR+AGPR total (~190) pins us at
// 2 waves/SIMD / 1 block/CU no matter what LDS is; budget here ~230 <= 256.
template <bool USE_PARTIAL>
__global__ __launch_bounds__(512, 2) void ffn_kernel(
    const float* __restrict__ x,
    const unsigned short* __restrict__ W1p,
    const unsigned short* __restrict__ W2p,
    const float* __restrict__ b1, const float* __restrict__ b2,
    const int* __restrict__ counts,
    const int* __restrict__ tok_list, const float* __restrict__ wt_list,
    float* __restrict__ partial,
    float* __restrict__ out) {
  __shared__ unsigned short Xs[64 * 512];   // 64 KB
  __shared__ unsigned short Hs[64 * 256];   // 32 KB single buffer (256F iter)

  const int e = blockIdx.x & 7;        // expert -> XCD pinning
  const int tile = blockIdx.x >> 3;
  const int cnt = counts[e];
  const int m0 = tile * 64;
  if (m0 >= cnt) return;
  const int rows = min(64, cnt - m0);

  int pbase = 0;
  if (USE_PARTIAL) {
    #pragma unroll
    for (int i = 0; i < NEXP; i++) pbase += (i < e) ? counts[i] : 0;
  }

  const int tid = threadIdx.x;
  const int wave = tid >> 6, lane = tid & 63;
  const int g = lane >> 4, ln = lane & 15;

  // W1 base for this wave's ft pair (ftA = fc/16 + 2*wave, ftB = ftA+1).
  const unsigned short* const w1b_first =
      W1p + ((long)(e * 128 + wave * 2) * 16) * 512 + lane * 8;
  const unsigned short* w1b = w1b_first;

  bf16x8 wP[8], wQ[8], w2rA[4], w2rB[4];
  // prologue W1 batch 0 issued BEFORE staging: latency hides under X gather
  LD4x2(wP, 0);

  // stage gathered X tile (fp32 -> bf16), XOR-swizzled; nontemporal reads
  #pragma unroll 4
  for (int c = tid; c < 64 * 128; c += 512) {
    int r = c >> 7, q = c & 127;
    ushort4 bv = {0, 0, 0, 0};
    if (r < rows) {
      int tk = tok_list[e * T_TOKENS + m0 + r];
      const f32x4 v = __builtin_nontemporal_load((const f32x4*)(x + (long)tk * DIM + q * 4));
      bv.x = f2bf(v[0]); bv.y = f2bf(v[1]); bv.z = f2bf(v[2]); bv.w = f2bf(v[3]);
    }
    int addr = r * 512 + ((((q >> 1) ^ (r & 7)) << 3) | ((q & 1) << 2));
    *(ushort4*)&Xs[addr] = bv;
  }
  LGKM_BARRIER();

  const f32x4 zero4 = {0.f, 0.f, 0.f, 0.f};
  f32x4 Yacc[4][4];
  #pragma unroll
  for (int a = 0; a < 4; a++)
    #pragma unroll
    for (int b = 0; b < 4; b++) Yacc[a][b] = zero4;

  const int xsw = ln & 7;

  for (int fc = 0; fc < FDIM; fc += 256) {
    f32x4 HA[4], HB[4];
    #pragma unroll
    for (int mt = 0; mt < 4; mt++) { HA[mt] = zero4; HB[mt] = zero4; }

    // GEMM1: 4 batches of 4 kci, ping-pong wP/wQ; each batch's wait covered
    // by the previous batch's 32 MFMAs (+16 LDS reads).
    LD4x2(wQ, 4);
    __builtin_amdgcn_s_setprio(1);
    MF4x2(wP, 0);
    __builtin_amdgcn_s_setprio(0);
    LD4x2(wP, 8);
    __builtin_amdgcn_s_setprio(1);
    MF4x2(wQ, 4);
    __builtin_amdgcn_s_setprio(0);
    LD4x2(wQ, 12);
    __builtin_amdgcn_s_setprio(1);
    MF4x2(wP, 8);
    __builtin_amdgcn_s_setprio(0);
    LD_W2B(w2rA, 0);   // GEMM2 kl 0 prefetch (survives barriers)
    __builtin_amdgcn_s_setprio(1);
    MF4x2(wQ, 12);
    __builtin_amdgcn_s_setprio(0);
    LD_W2B(w2rB, 1);   // GEMM2 kl 1 prefetch
    // next-iter W1 base (last iter re-points at iter-0 lines; those loads
    // are valid reads whose values are never consumed)
    w1b = (fc + 256 < FDIM) ? (w1b + 16 * 16 * 512) : w1b_first;
    LD4x2(wP, 0);      // next-iter batch 0 (cross-iter prefetch)

    // barrier A: all waves done reading Hs (prev iter's GEMM2) before rewrite
    LGKM_BARRIER();

    // bias + relu -> Hs. fl = (2*wave+p)*16 + ln; key m&15 spreads write
    // lanes over all 32 banks (2-way, free).
    {
      float b1vA = b1[e * FDIM + fc + (wave * 2) * 16 + ln];
      float b1vB = b1[e * FDIM + fc + (wave * 2 + 1) * 16 + ln];
      int flA = (wave * 2) * 16 + ln;
      int flB = flA + 16;
      #pragma unroll
      for (int mt = 0; mt < 4; mt++) {
        #pragma unroll
        for (int i = 0; i < 4; i++) {
          int m = mt * 16 + g * 4 + i;
          int aA = m * 256 + ((((flA >> 3) ^ (m & 15)) << 3) | (flA & 7));
          int aB = m * 256 + ((((flB >> 3) ^ (m & 15)) << 3) | (flB & 7));
          Hs[aA] = f2bf(fmaxf(HA[mt][i] + b1vA, 0.f));
          Hs[aB] = f2bf(fmaxf(HB[mt][i] + b1vB, 0.f));
        }
      }
    }
    // barrier B: Hs writes visible; weight prefetches stay in flight
    LGKM_BARRIER();

    // GEMM2 over 256 F = 8 kl chunks; rolling 2-deep W2 prefetch
    __builtin_amdgcn_s_setprio(1);
    #pragma unroll
    for (int kl = 0; kl < 8; kl++) {
      const bf16x8* w2c = (kl & 1) ? w2rB : w2rA;
      bf16x8 ha[4];
      #pragma unroll
      for (int mt = 0; mt < 4; mt++) {
        int m = mt * 16 + ln;
        ha[mt] = *(const bf16x8*)&Hs[m * 256 + (((kl * 4 + g) ^ (m & 15)) << 3)];
      }
      #pragma unroll
      for (int nt = 0; nt < 4; nt++)
        #pragma unroll
        for (int mt = 0; mt < 4; mt++)
          Yacc[mt][nt] = __builtin_amdgcn_mfma_f32_16x16x32_bf16(ha[mt], w2c[nt], Yacc[mt][nt], 0, 0, 0);
      if (kl < 6) {
        __builtin_amdgcn_s_setprio(0);
        if (kl & 1) { LD_W2B(w2rB, kl + 2); } else { LD_W2B(w2rA, kl + 2); }
        __builtin_amdgcn_s_setprio(1);
      }
    }
    __builtin_amdgcn_s_setprio(0);
  }

  // epilogue: (Y + b2) * token_weight
  #pragma unroll
  for (int mt = 0; mt < 4; mt++) {
    #pragma unroll
    for (int i = 0; i < 4; i++) {
      int m = mt * 16 + g * 4 + i;
      if (m < rows) {
        float w = wt_list[e * T_TOKENS + m0 + m];
        if (USE_PARTIAL) {
          float* dst = partial + ((long)(pbase + m0 + m)) * DIM;
          #pragma unroll
          for (int nt = 0; nt < 4; nt++) {
            int d = (wave * 4 + nt) * 16 + ln;
            __builtin_nontemporal_store((Yacc[mt][nt][i] + b2[e * DIM + d]) * w, dst + d);
          }
        } else {
          int tk = tok_list[e * T_TOKENS + m0 + m];
          #pragma unroll
          for (int nt = 0; nt < 4; nt++) {
            int d = (wave * 4 + nt) * 16 + ln;
            float v = (Yacc[mt][nt][i] + b2[e * DIM + d]) * w;
            atomicAdd(out + (long)tk * DIM + d, v);
          }
        }
      }
    }
  }
}

// out[t] = partial[row(slots[2t])] + partial[row(slots[2t+1])] ; pure
// streaming, no RMW. row(slot) = prefix[e] + s with slot = e*T_TOKENS + s.
__global__ __launch_bounds__(256) void combine_kernel(
    const float* __restrict__ partial, const int* __restrict__ slots,
    const int* __restrict__ counts, float* __restrict__ out) {
  __shared__ int pre[NEXP];
  if (threadIdx.x == 0) {
    int a = 0;
    #pragma unroll
    for (int i = 0; i < NEXP; i++) { pre[i] = a; a += counts[i]; }
  }
  __syncthreads();
  const int tid = threadIdx.x;
  const int tk = blockIdx.x * 2 + (tid >> 7);
  const int q = (tid & 127) << 2;
  const int2 sp = *(const int2*)(slots + 2 * tk);
  const long r0 = pre[sp.x >> 15] + (sp.x & (T_TOKENS - 1));
  const long r1 = pre[sp.y >> 15] + (sp.y & (T_TOKENS - 1));
  const f32x4 a = __builtin_nontemporal_load((const f32x4*)(partial + r0 * DIM + q));
  const f32x4 b = __builtin_nontemporal_load((const f32x4*)(partial + r1 * DIM + q));
  f32x4 r = a + b;
  __builtin_nontemporal_store(r, (f32x4*)(out + (long)tk * DIM + q));
}

extern "C" void kernel_launch(void* const* d_in, const int* in_sizes, int n_in,
                              void* d_out, int out_size, void* d_ws, size_t ws_size,
                              hipStream_t stream) {
  (void)in_sizes; (void)n_in; (void)out_size;
  const float* x  = (const float*)d_in[0];
  const float* Wr = (const float*)d_in[1];
  const float* br = (const float*)d_in[2];
  const float* W1 = (const float*)d_in[3];
  const float* b1 = (const float*)d_in[4];
  const float* W2 = (const float*)d_in[5];
  const float* b2 = (const float*)d_in[6];
  float* out = (float*)d_out;

  char* ws = (char*)d_ws;
  // layout (bytes):
  //   counts   @ 0          (1,024)
  //   tok_list @ 1,024      (1,048,576)
  //   wt_list  @ 1,049,600  (1,048,576)
  //   slots    @ 2,098,176  (262,144)
  //   W1p      @ 2,360,320  (16,777,216)
  //   W2p      @ 19,137,536 (16,777,216)
  //   partial  @ 35,914,752 (134,217,728 = 2*T rows x 512 f32) -> end 170,132,480
  int*            counts   = (int*)(ws);
  int*            tok_list = (int*)(ws + 1024);
  float*          wt_list  = (float*)(ws + 1049600);
  int*            slots    = (int*)(ws + 2098176);
  unsigned short* W1p      = (unsigned short*)(ws + 2360320);
  unsigned short* W2p      = (unsigned short*)(ws + 19137536);
  float*          partial  = (float*)(ws + 35914752);
  const size_t need_partial = 35914752ull + (size_t)T_TOKENS * 2 * DIM * sizeof(float);
  const bool use_partial = ws_size >= need_partial;

  hipMemsetAsync(counts, 0, 1024, stream);
  pack_w1_kernel<<<NEXP * 128, 256, 0, stream>>>(W1, W1p);
  pack_w2_kernel<<<NEXP * 32, 256, 0, stream>>>(W2, W2p);

  if (use_partial) {
    router_kernel<<<T_TOKENS / 256, 256, 0, stream>>>(x, Wr, br, counts, tok_list, wt_list, slots);
    ffn_kernel<true><<<T_TOKENS / 64 * NEXP, 512, 0, stream>>>(
        x, W1p, W2p, b1, b2, counts, tok_list, wt_list, partial, out);
    combine_kernel<<<T_TOKENS / 2, 256, 0, stream>>>(partial, slots, counts, out);
  } else {
    // fallback: original atomic-accumulate path
    hipMemsetAsync(out, 0, (size_t)T_TOKENS * DIM * sizeof(float), stream);
    router_kernel<<<T_TOKENS / 256, 256, 0, stream>>>(x, Wr, br, counts, tok_list, wt_list, nullptr);
    ffn_kernel<false><<<T_TOKENS / 64 * NEXP, 512, 0, stream>>>(
        x, W1p, W2p, b1, b2, counts, tok_list, wt_list, nullptr, out);
  }
}